// Round 3
// baseline (251.871 us; speedup 1.0000x reference)
//
#include <hip/hip_runtime.h>
#include <math.h>

#define SPAT 96
#define PLANE (SPAT*SPAT*SPAT)   /* 884736 */
#define IMG   (SPAT*SPAT)        /* 9216   */
#define NCHUNK (64 * SPAT * SPAT * 24)   /* 14,155,776 float4 output chunks */
#define ZBLOCKS (NCHUNK / 256)           /* 55,296 */
#define SLAB_BLOCKS 576                  /* 4 sb * 144 */

// ---------------------------------------------------------------------------
// 4x4 matrix inverse (adjugate)
// ---------------------------------------------------------------------------
__device__ inline void invert4(const float m[16], float inv[16]) {
    inv[0]  =  m[5]*m[10]*m[15] - m[5]*m[11]*m[14] - m[9]*m[6]*m[15] + m[9]*m[7]*m[14] + m[13]*m[6]*m[11] - m[13]*m[7]*m[10];
    inv[4]  = -m[4]*m[10]*m[15] + m[4]*m[11]*m[14] + m[8]*m[6]*m[15] - m[8]*m[7]*m[14] - m[12]*m[6]*m[11] + m[12]*m[7]*m[10];
    inv[8]  =  m[4]*m[9]*m[15]  - m[4]*m[11]*m[13] - m[8]*m[5]*m[15] + m[8]*m[7]*m[13] + m[12]*m[5]*m[11] - m[12]*m[7]*m[9];
    inv[12] = -m[4]*m[9]*m[14]  + m[4]*m[10]*m[13] + m[8]*m[5]*m[14] - m[8]*m[6]*m[13] - m[12]*m[5]*m[10] + m[12]*m[6]*m[9];
    inv[1]  = -m[1]*m[10]*m[15] + m[1]*m[11]*m[14] + m[9]*m[2]*m[15] - m[9]*m[3]*m[14] - m[13]*m[2]*m[11] + m[13]*m[3]*m[10];
    inv[5]  =  m[0]*m[10]*m[15] - m[0]*m[11]*m[14] - m[8]*m[2]*m[15] + m[8]*m[3]*m[14] + m[12]*m[2]*m[11] - m[12]*m[3]*m[10];
    inv[9]  = -m[0]*m[9]*m[15]  + m[0]*m[11]*m[13] + m[8]*m[1]*m[15] - m[8]*m[3]*m[13] - m[12]*m[1]*m[11] + m[12]*m[3]*m[9];
    inv[13] =  m[0]*m[9]*m[14]  - m[0]*m[10]*m[13] - m[8]*m[1]*m[14] + m[8]*m[2]*m[13] + m[12]*m[1]*m[10] - m[12]*m[2]*m[9];
    inv[2]  =  m[1]*m[6]*m[15]  - m[1]*m[7]*m[14]  - m[5]*m[2]*m[15] + m[5]*m[3]*m[14] + m[13]*m[2]*m[7]  - m[13]*m[3]*m[6];
    inv[6]  = -m[0]*m[6]*m[15]  + m[0]*m[7]*m[14]  + m[4]*m[2]*m[15] - m[4]*m[3]*m[14] - m[12]*m[2]*m[7]  + m[12]*m[3]*m[6];
    inv[10] =  m[0]*m[5]*m[15]  - m[0]*m[7]*m[13]  - m[4]*m[1]*m[15] + m[4]*m[3]*m[13] + m[12]*m[1]*m[7]  - m[12]*m[3]*m[5];
    inv[14] = -m[0]*m[5]*m[14]  + m[0]*m[6]*m[13]  + m[4]*m[1]*m[14] - m[4]*m[2]*m[13] - m[12]*m[1]*m[6]  + m[12]*m[2]*m[5];
    inv[3]  = -m[1]*m[6]*m[11]  + m[1]*m[7]*m[10]  + m[5]*m[2]*m[11] - m[5]*m[3]*m[10] - m[9]*m[2]*m[7]   + m[9]*m[3]*m[6];
    inv[7]  =  m[0]*m[6]*m[11]  - m[0]*m[7]*m[10]  - m[4]*m[2]*m[11] + m[4]*m[3]*m[10] + m[8]*m[2]*m[7]   - m[8]*m[3]*m[6];
    inv[11] = -m[0]*m[5]*m[11]  + m[0]*m[7]*m[9]   + m[4]*m[1]*m[11] - m[4]*m[3]*m[9]  - m[8]*m[1]*m[7]   + m[8]*m[3]*m[5];
    inv[15] =  m[0]*m[5]*m[10]  - m[0]*m[6]*m[9]   - m[4]*m[1]*m[10] + m[4]*m[2]*m[9]  + m[8]*m[1]*m[6]   - m[8]*m[2]*m[5];
    float det  = m[0]*inv[0] + m[1]*inv[4] + m[2]*inv[8] + m[3]*inv[12];
    float rdet = 1.0f / det;
    for (int i = 0; i < 16; ++i) inv[i] *= rdet;
}

// ---------------------------------------------------------------------------
// Prep: per (slice,batch) pair, column-normalize affine, invert, fold
// affine_grid + grid_sample maps into M: (w,h,d)->(ix,iy,iz).
// Layout per sb (16 floats): [0..3]=x row(w,h,d,const), [4..7]=y, [8..11]=z,
// [12]=1/Mxw (0 if degenerate), [13..15] pad.
// ---------------------------------------------------------------------------
__global__ void prep_kernel(const float* __restrict__ aff_in,
                            float* __restrict__ Mout) {
    int t = threadIdx.x;
    if (t >= 4) return;
    float A[16];
    #pragma unroll
    for (int i = 0; i < 16; ++i) A[i] = aff_in[t * 16 + i];
    #pragma unroll
    for (int j = 0; j < 3; ++j) {
        float z = sqrtf(A[0*4+j]*A[0*4+j] + A[1*4+j]*A[1*4+j] + A[2*4+j]*A[2*4+j]);
        float rz = 1.0f / z;
        #pragma unroll
        for (int i = 0; i < 4; ++i) A[i*4+j] *= rz;
    }
    float inv[16];
    invert4(A, inv);
    float* M = Mout + t * 16;
    #pragma unroll
    for (int r = 0; r < 3; ++r) {
        float T0 = inv[r*4+0], T1 = inv[r*4+1], T2 = inv[r*4+2], T3 = inv[r*4+3];
        // ix = T0*w + T1*h + T2*d + [-47.5*(T0+T1+T2) + 48*T3 + 47.5]
        M[r*4+0] = T0;
        M[r*4+1] = T1;
        M[r*4+2] = T2;
        M[r*4+3] = -47.5f * (T0 + T1 + T2) + 48.0f * T3 + 47.5f;
    }
    float Mxw = M[0];
    M[12] = (fabsf(Mxw) > 1e-6f) ? (1.0f / Mxw) : 0.0f;
    M[13] = 0.f; M[14] = 0.f; M[15] = 0.f;
}

// Shared interval: w's where the warped source plane (x==48) may contribute:
// |Mxw*w + bx - 48| < 1.  MUST be evaluated identically in both paths.
__device__ inline void w_interval(float Mxw, float rMxw, float bx,
                                  int& wlo, int& whi) {
    if (fabsf(Mxw) > 1e-6f) {
        float w1 = (47.0f - bx) * rMxw;
        float w2 = (49.0f - bx) * rMxw;
        float wmin = fminf(w1, w2), wmax = fmaxf(w1, w2);
        wlo = max((int)ceilf(wmin), 0);
        whi = min((int)floorf(wmax), SPAT - 1);
    } else {
        bool in = fabsf(bx - 48.0f) < 1.0f;
        wlo = in ? 0 : 1;
        whi = in ? SPAT - 1 : 0;
    }
}

// ---------------------------------------------------------------------------
// Fused kernel.
// blockIdx.x <  SLAB_BLOCKS : slab path — one thread = (sb,d,h,cg); writes
//   full float4 chunks covering [wlo,whi] (zeros where wx<=0) for 4 channels.
// blockIdx.x >= SLAB_BLOCKS : zero path — one thread = one output float4
//   chunk (c,d,h,w4); stores zeros unless the chunk lies in the slab interval
//   (then the slab path owns it).  Each output chunk written exactly once.
// Slab blocks first so their latency-bound gathers overlap the streaming tail.
// ---------------------------------------------------------------------------
__global__ __launch_bounds__(256) void fused_kernel(
        const float* __restrict__ xin,   // [2,32,96,96]
        const float* __restrict__ Mw,    // [4][16]
        float* __restrict__ out) {       // [2,32,96,96,96]
    int bid = blockIdx.x;
    if (bid < SLAB_BLOCKS) {
        // ---------------- slab path ----------------
        int sb  = bid / 144;             // s*2 + b
        int rem = bid - sb * 144;
        int t   = rem * 256 + threadIdx.x;   // 0..36863
        int cg  = t & 3;
        int hd  = t >> 2;
        int h   = hd % SPAT;
        int d   = hd / SPAT;
        int s   = sb >> 1;
        int b   = sb & 1;

        const float* M = Mw + sb * 16;
        float Mxw = M[0], Mxh = M[1], Mxd = M[2],  Mx0 = M[3];
        float Myw = M[4], Myh = M[5], Myd = M[6],  My0 = M[7];
        float Mzw = M[8], Mzh = M[9], Mzd = M[10], Mz0 = M[11];
        float rMxw = M[12];

        float fh = (float)h, fd = (float)d;
        float bx = Mxh * fh + Mxd * fd + Mx0;
        int wlo, whi;
        w_interval(Mxw, rMxw, bx, wlo, whi);
        if (wlo > whi) return;
        int qlo = wlo >> 2, qhi = whi >> 2;

        float by = Myh * fh + Myd * fd + My0;
        float bz = Mzh * fh + Mzd * fd + Mz0;

        size_t cbase = (size_t)(b * 32 + s * 16 + cg * 4);
        const float* img = xin + cbase * (size_t)IMG;
        float* op = out + cbase * (size_t)PLANE + ((size_t)d * SPAT + h) * SPAT;

        for (int q = qlo; q <= qhi; ++q) {
            float v[4][4];               // [c][j]
            #pragma unroll
            for (int j = 0; j < 4; ++j) {
                float fw = (float)(4 * q + j);
                float ix = Mxw * fw + bx;
                float wx = 1.0f - fabsf(ix - 48.0f);
                if (wx > 0.0f) {
                    float iy = Myw * fw + by;
                    float iz = Mzw * fw + bz;
                    float yf = floorf(iy), zf = floorf(iz);
                    float fy = iy - yf,    fz = iz - zf;
                    int y0 = (int)yf, z0 = (int)zf;
                    bool vy0 = (y0 >= 0)  & (y0 <  SPAT);
                    bool vy1 = (y0 >= -1) & (y0 <  SPAT - 1);
                    bool vz0 = (z0 >= 0)  & (z0 <  SPAT);
                    bool vz1 = (z0 >= -1) & (z0 <  SPAT - 1);
                    int y0c = min(max(y0, 0),     SPAT - 1);
                    int y1c = min(max(y0 + 1, 0), SPAT - 1);
                    int z0c = min(max(z0, 0),     SPAT - 1);
                    int z1c = min(max(z0 + 1, 0), SPAT - 1);
                    float wy0 = 1.0f - fy, wy1 = fy;
                    float wz0 = 1.0f - fz, wz1 = fz;
                    float w00 = wx * wz0 * wy0 * ((vz0 & vy0) ? 1.0f : 0.0f);
                    float w01 = wx * wz0 * wy1 * ((vz0 & vy1) ? 1.0f : 0.0f);
                    float w10 = wx * wz1 * wy0 * ((vz1 & vy0) ? 1.0f : 0.0f);
                    float w11 = wx * wz1 * wy1 * ((vz1 & vy1) ? 1.0f : 0.0f);
                    int o00 = z0c * SPAT + y0c, o01 = z0c * SPAT + y1c;
                    int o10 = z1c * SPAT + y0c, o11 = z1c * SPAT + y1c;
                    #pragma unroll
                    for (int c = 0; c < 4; ++c) {
                        const float* ic = img + (size_t)c * IMG;
                        v[c][j] = w00 * ic[o00] + w01 * ic[o01]
                                + w10 * ic[o10] + w11 * ic[o11];
                    }
                } else {
                    #pragma unroll
                    for (int c = 0; c < 4; ++c) v[c][j] = 0.0f;
                }
            }
            #pragma unroll
            for (int c = 0; c < 4; ++c) {
                *reinterpret_cast<float4*>(op + (size_t)c * PLANE + 4 * q) =
                    make_float4(v[c][0], v[c][1], v[c][2], v[c][3]);
            }
        }
    } else {
        // ---------------- zero path ----------------
        int g  = (bid - SLAB_BLOCKS) * 256 + threadIdx.x;  // chunk id
        int w4 = g % 24;
        int r1 = g / 24;
        int h  = r1 % SPAT;
        int r2 = r1 / SPAT;          // block-uniform (2304 chunks per (c,d))
        int d  = r2 % SPAT;
        int c  = r2 / SPAT;          // 0..63 = b*32 + ch
        int b  = c >> 5;
        int s  = (c >> 4) & 1;
        int sb = s * 2 + b;

        const float* M = Mw + sb * 16;
        float Mxw = M[0], Mxh = M[1], Mxd = M[2], Mx0 = M[3];
        float rMxw = M[12];

        float bx = Mxh * (float)h + Mxd * (float)d + Mx0;
        int wlo, whi;
        w_interval(Mxw, rMxw, bx, wlo, whi);
        bool owned_by_slab = (wlo <= whi) && (w4 >= (wlo >> 2)) && (w4 <= (whi >> 2));
        if (!owned_by_slab) {
            float4 z = make_float4(0.f, 0.f, 0.f, 0.f);
            *reinterpret_cast<float4*>(
                out + (size_t)c * PLANE + ((size_t)d * SPAT + h) * SPAT + 4 * w4) = z;
        }
    }
}

extern "C" void kernel_launch(void* const* d_in, const int* in_sizes, int n_in,
                              void* d_out, int out_size, void* d_ws, size_t ws_size,
                              hipStream_t stream) {
    const float* x   = (const float*)d_in[0];   // [2,32,96,96] fp32
    const float* aff = (const float*)d_in[1];   // [2,2,4,4]    fp32
    float* out = (float*)d_out;                 // [2,32,96,96,96] fp32
    float* M   = (float*)d_ws;                  // 4*16 floats scratch

    prep_kernel<<<1, 64, 0, stream>>>(aff, M);
    fused_kernel<<<SLAB_BLOCKS + ZBLOCKS, 256, 0, stream>>>(x, M, out);
}

// Round 4
// 237.234 us; speedup vs baseline: 1.0617x; 1.0617x over previous
//
#include <hip/hip_runtime.h>
#include <math.h>

#define SPAT 96
#define PLANE (SPAT*SPAT*SPAT)   /* 884736 */
#define IMG   (SPAT*SPAT)        /* 9216   */
#define OUT_FLOATS (64 * PLANE)  /* 2*32*96^3 = 56,623,104 */

// ---------------------------------------------------------------------------
// 4x4 matrix inverse (adjugate)
// ---------------------------------------------------------------------------
__device__ inline void invert4(const float m[16], float inv[16]) {
    inv[0]  =  m[5]*m[10]*m[15] - m[5]*m[11]*m[14] - m[9]*m[6]*m[15] + m[9]*m[7]*m[14] + m[13]*m[6]*m[11] - m[13]*m[7]*m[10];
    inv[4]  = -m[4]*m[10]*m[15] + m[4]*m[11]*m[14] + m[8]*m[6]*m[15] - m[8]*m[7]*m[14] - m[12]*m[6]*m[11] + m[12]*m[7]*m[10];
    inv[8]  =  m[4]*m[9]*m[15]  - m[4]*m[11]*m[13] - m[8]*m[5]*m[15] + m[8]*m[7]*m[13] + m[12]*m[5]*m[11] - m[12]*m[7]*m[9];
    inv[12] = -m[4]*m[9]*m[14]  + m[4]*m[10]*m[13] + m[8]*m[5]*m[14] - m[8]*m[6]*m[13] - m[12]*m[5]*m[10] + m[12]*m[6]*m[9];
    inv[1]  = -m[1]*m[10]*m[15] + m[1]*m[11]*m[14] + m[9]*m[2]*m[15] - m[9]*m[3]*m[14] - m[13]*m[2]*m[11] + m[13]*m[3]*m[10];
    inv[5]  =  m[0]*m[10]*m[15] - m[0]*m[11]*m[14] - m[8]*m[2]*m[15] + m[8]*m[3]*m[14] + m[12]*m[2]*m[11] - m[12]*m[3]*m[10];
    inv[9]  = -m[0]*m[9]*m[15]  + m[0]*m[11]*m[13] + m[8]*m[1]*m[15] - m[8]*m[3]*m[13] - m[12]*m[1]*m[11] + m[12]*m[3]*m[9];
    inv[13] =  m[0]*m[9]*m[14]  - m[0]*m[10]*m[13] - m[8]*m[1]*m[14] + m[8]*m[2]*m[13] + m[12]*m[1]*m[10] - m[12]*m[2]*m[9];
    inv[2]  =  m[1]*m[6]*m[15]  - m[1]*m[7]*m[14]  - m[5]*m[2]*m[15] + m[5]*m[3]*m[14] + m[13]*m[2]*m[7]  - m[13]*m[3]*m[6];
    inv[6]  = -m[0]*m[6]*m[15]  + m[0]*m[7]*m[14]  + m[4]*m[2]*m[15] - m[4]*m[3]*m[14] - m[12]*m[2]*m[7]  + m[12]*m[3]*m[6];
    inv[10] =  m[0]*m[5]*m[15]  - m[0]*m[7]*m[13]  - m[4]*m[1]*m[15] + m[4]*m[3]*m[13] + m[12]*m[1]*m[7]  - m[12]*m[3]*m[5];
    inv[14] = -m[0]*m[5]*m[14]  + m[0]*m[6]*m[13]  + m[4]*m[1]*m[14] - m[4]*m[2]*m[13] - m[12]*m[1]*m[6]  + m[12]*m[2]*m[5];
    inv[3]  = -m[1]*m[6]*m[11]  + m[1]*m[7]*m[10]  + m[5]*m[2]*m[11] - m[5]*m[3]*m[10] - m[9]*m[2]*m[7]   + m[9]*m[3]*m[6];
    inv[7]  =  m[0]*m[6]*m[11]  - m[0]*m[7]*m[10]  - m[4]*m[2]*m[11] + m[4]*m[3]*m[10] + m[8]*m[2]*m[7]   - m[8]*m[3]*m[6];
    inv[11] = -m[0]*m[5]*m[11]  + m[0]*m[7]*m[9]   + m[4]*m[1]*m[11] - m[4]*m[3]*m[9]  - m[8]*m[1]*m[7]   + m[8]*m[3]*m[5];
    inv[15] =  m[0]*m[5]*m[10]  - m[0]*m[6]*m[9]   - m[4]*m[1]*m[10] + m[4]*m[2]*m[9]  + m[8]*m[1]*m[6]   - m[8]*m[2]*m[5];
    float det  = m[0]*inv[0] + m[1]*inv[4] + m[2]*inv[8] + m[3]*inv[12];
    float rdet = 1.0f / det;
    for (int i = 0; i < 16; ++i) inv[i] *= rdet;
}

// ---------------------------------------------------------------------------
// Zero the whole output: pure streaming float4 stores. Keep this kernel
// instruction-minimal — R3 showed any per-chunk logic here costs more than
// it saves (proven 6.6 TB/s in this form).
// ---------------------------------------------------------------------------
__global__ __launch_bounds__(256) void zero_kernel(float4* __restrict__ out) {
    const size_t n4 = OUT_FLOATS / 4;          // 14,155,776
    size_t i = (size_t)blockIdx.x * 256 + threadIdx.x;
    size_t stride = (size_t)gridDim.x * 256;
    float4 z = make_float4(0.f, 0.f, 0.f, 0.f);
    for (; i < n4; i += stride) out[i] = z;
}

// ---------------------------------------------------------------------------
// Slab writer: only voxels where the warped source plane x==48 contributes
// (|ix-48| < 1, ix linear in w -> closed-form w interval per (sb,d,h)).
// One thread = (sb, d, h, channel-quad, q-parity); writes float4 chunks
// (zeros where wx<=0 inside a chunk). Runs after zero_kernel; overwrites
// only chunks inside its interval. Folded affine computed per-block by
// thread 0 into LDS (no separate prep launch).
// grid = (288, 4): blockIdx.y = sb; 288*256 = 96d * 96h * 4cg * 2qpar.
// ---------------------------------------------------------------------------
__global__ __launch_bounds__(256) void slab_kernel(
        const float* __restrict__ xin,   // [2,32,96,96]
        const float* __restrict__ aff_in,// [2,2,4,4]
        float* __restrict__ out) {       // [2,32,96,96,96]
    __shared__ float Ms[12];
    int sb = blockIdx.y;                 // s*2 + b
    if (threadIdx.x == 0) {
        float A[16];
        #pragma unroll
        for (int i = 0; i < 16; ++i) A[i] = aff_in[sb * 16 + i];
        #pragma unroll
        for (int j = 0; j < 3; ++j) {    // column-normalize by zooms
            float z = sqrtf(A[0*4+j]*A[0*4+j] + A[1*4+j]*A[1*4+j] + A[2*4+j]*A[2*4+j]);
            float rz = 1.0f / z;
            #pragma unroll
            for (int i = 0; i < 4; ++i) A[i*4+j] *= rz;
        }
        float inv[16];
        invert4(A, inv);
        #pragma unroll
        for (int r = 0; r < 3; ++r) {
            float T0 = inv[r*4+0], T1 = inv[r*4+1], T2 = inv[r*4+2], T3 = inv[r*4+3];
            // ix = T0*w + T1*h + T2*d + [-47.5*(T0+T1+T2) + 48*T3 + 47.5]
            Ms[r*4+0] = T0;
            Ms[r*4+1] = T1;
            Ms[r*4+2] = T2;
            Ms[r*4+3] = -47.5f * (T0 + T1 + T2) + 48.0f * T3 + 47.5f;
        }
    }
    __syncthreads();

    int t    = blockIdx.x * 256 + threadIdx.x;   // 0..73727
    int cg   = t & 3;                            // channel quad
    int qpar = (t >> 2) & 1;                     // q parity (2x wave count)
    int hd   = t >> 3;
    int h    = hd % SPAT;
    int d    = hd / SPAT;
    int s    = sb >> 1;
    int b    = sb & 1;

    float Mxw = Ms[0], Mxh = Ms[1], Mxd = Ms[2],  Mx0 = Ms[3];
    float Myw = Ms[4], Myh = Ms[5], Myd = Ms[6],  My0 = Ms[7];
    float Mzw = Ms[8], Mzh = Ms[9], Mzd = Ms[10], Mz0 = Ms[11];

    float fh = (float)h, fd = (float)d;
    float bx = Mxh * fh + Mxd * fd + Mx0;

    // contributing w interval: |Mxw*w + bx - 48| < 1
    int wlo, whi;
    if (fabsf(Mxw) > 1e-6f) {
        float rMxw = 1.0f / Mxw;
        float w1 = (47.0f - bx) * rMxw;
        float w2 = (49.0f - bx) * rMxw;
        float wmin = fminf(w1, w2), wmax = fmaxf(w1, w2);
        wlo = max((int)ceilf(wmin), 0);
        whi = min((int)floorf(wmax), SPAT - 1);
    } else {
        bool in = fabsf(bx - 48.0f) < 1.0f;
        wlo = in ? 0 : 1;
        whi = in ? SPAT - 1 : 0;
    }
    if (wlo > whi) return;
    int qlo = (wlo >> 2) + qpar, qhi = whi >> 2;

    float by = Myh * fh + Myd * fd + My0;
    float bz = Mzh * fh + Mzd * fd + Mz0;

    size_t cbase = (size_t)(b * 32 + s * 16 + cg * 4);
    const float* img = xin + cbase * (size_t)IMG;
    float* op = out + cbase * (size_t)PLANE + ((size_t)d * SPAT + h) * SPAT;

    for (int q = qlo; q <= qhi; q += 2) {
        float v[4][4];                   // [c][j]
        #pragma unroll
        for (int j = 0; j < 4; ++j) {
            float fw = (float)(4 * q + j);
            float ix = Mxw * fw + bx;
            float wx = 1.0f - fabsf(ix - 48.0f);
            if (wx > 0.0f) {
                float iy = Myw * fw + by;
                float iz = Mzw * fw + bz;
                float yf = floorf(iy), zf = floorf(iz);
                float fy = iy - yf,    fz = iz - zf;
                int y0 = (int)yf, z0 = (int)zf;
                bool vy0 = (y0 >= 0)  & (y0 <  SPAT);
                bool vy1 = (y0 >= -1) & (y0 <  SPAT - 1);
                bool vz0 = (z0 >= 0)  & (z0 <  SPAT);
                bool vz1 = (z0 >= -1) & (z0 <  SPAT - 1);
                int y0c = min(max(y0, 0),     SPAT - 1);
                int y1c = min(max(y0 + 1, 0), SPAT - 1);
                int z0c = min(max(z0, 0),     SPAT - 1);
                int z1c = min(max(z0 + 1, 0), SPAT - 1);
                float wy0 = 1.0f - fy, wy1 = fy;
                float wz0 = 1.0f - fz, wz1 = fz;
                float w00 = wx * wz0 * wy0 * ((vz0 & vy0) ? 1.0f : 0.0f);
                float w01 = wx * wz0 * wy1 * ((vz0 & vy1) ? 1.0f : 0.0f);
                float w10 = wx * wz1 * wy0 * ((vz1 & vy0) ? 1.0f : 0.0f);
                float w11 = wx * wz1 * wy1 * ((vz1 & vy1) ? 1.0f : 0.0f);
                int o00 = z0c * SPAT + y0c, o01 = z0c * SPAT + y1c;
                int o10 = z1c * SPAT + y0c, o11 = z1c * SPAT + y1c;
                #pragma unroll
                for (int c = 0; c < 4; ++c) {
                    const float* ic = img + (size_t)c * IMG;
                    v[c][j] = w00 * ic[o00] + w01 * ic[o01]
                            + w10 * ic[o10] + w11 * ic[o11];
                }
            } else {
                #pragma unroll
                for (int c = 0; c < 4; ++c) v[c][j] = 0.0f;
            }
        }
        #pragma unroll
        for (int c = 0; c < 4; ++c) {
            *reinterpret_cast<float4*>(op + (size_t)c * PLANE + 4 * q) =
                make_float4(v[c][0], v[c][1], v[c][2], v[c][3]);
        }
    }
}

extern "C" void kernel_launch(void* const* d_in, const int* in_sizes, int n_in,
                              void* d_out, int out_size, void* d_ws, size_t ws_size,
                              hipStream_t stream) {
    const float* x   = (const float*)d_in[0];   // [2,32,96,96] fp32
    const float* aff = (const float*)d_in[1];   // [2,2,4,4]    fp32
    float* out = (float*)d_out;                 // [2,32,96,96,96] fp32

    // 1) stream-zero the full output (write-bound floor, ~34 us @ 6.6 TB/s)
    zero_kernel<<<4096, 256, 0, stream>>>((float4*)out);

    // 2) overwrite only the tilted-slab chunks (short serialized tail)
    dim3 grid(288, 4);                          // 288*256 = 96d*96h*4cg*2qpar
    slab_kernel<<<grid, 256, 0, stream>>>(x, aff, out);
}